// Round 1
// baseline (7886.831 us; speedup 1.0000x reference)
//
#include <hip/hip_runtime.h>
#include <math.h>

// Problem constants
#define BS_    256
#define FEAT_  2048
#define EMB_   512
#define MEM_   1024
#define VOCAB_ 10000
#define TT_    32
#define NSTEP  31          // T-1 steps
#define NTILE_V 157        // ceil(10000/64)

__device__ __forceinline__ float sigmoidf_(float x) { return 1.0f / (1.0f + __expf(-x)); }

// ---------------------------------------------------------------------------
// Generic C = A(MxK) @ B(NxK)^T + bias, fp32, 64x64 tile, 4x4 microtile
// ---------------------------------------------------------------------------
__global__ __launch_bounds__(256) void gemm_nt_bias_k(
    const float* __restrict__ A, const float* __restrict__ B,
    const float* __restrict__ bias, float* __restrict__ C,
    int M, int N, int K) {
  __shared__ float As[16][65];
  __shared__ float Bs[16][65];
  int tid = threadIdx.x;
  int bx = blockIdx.x, by = blockIdx.y;
  int tx = tid & 15, ty = tid >> 4;
  float acc[4][4] = {};
  for (int k0 = 0; k0 < K; k0 += 16) {
#pragma unroll
    for (int i = 0; i < 4; ++i) {
      int idx = tid + i * 256;
      int m = idx >> 4, kk = idx & 15;
      int gm = by * 64 + m;
      As[kk][m] = (gm < M) ? A[(size_t)gm * K + k0 + kk] : 0.f;
    }
#pragma unroll
    for (int i = 0; i < 4; ++i) {
      int idx = tid + i * 256;
      int n = idx >> 4, kk = idx & 15;
      int gn = bx * 64 + n;
      Bs[kk][n] = (gn < N) ? B[(size_t)gn * K + k0 + kk] : 0.f;
    }
    __syncthreads();
#pragma unroll
    for (int kk = 0; kk < 16; ++kk) {
      float a[4], b[4];
#pragma unroll
      for (int i = 0; i < 4; ++i) a[i] = As[kk][ty * 4 + i];
#pragma unroll
      for (int j = 0; j < 4; ++j) b[j] = Bs[kk][tx * 4 + j];
#pragma unroll
      for (int i = 0; i < 4; ++i)
#pragma unroll
        for (int j = 0; j < 4; ++j) acc[i][j] += a[i] * b[j];
    }
    __syncthreads();
  }
#pragma unroll
  for (int i = 0; i < 4; ++i) {
    int gm = by * 64 + ty * 4 + i;
    if (gm >= M) continue;
#pragma unroll
    for (int j = 0; j < 4; ++j) {
      int gn = bx * 64 + tx * 4 + j;
      if (gn < N) C[(size_t)gm * N + gn] = acc[i][j] + bias[gn];
    }
  }
}

// ---------------------------------------------------------------------------
// gates = emb[caption[:,t]] @ W_ih^T + b_ih + h @ W_hh^T + b_hh
// Virtual concat K = 512 + 1024.  M=256, N=4096 fixed.
// ---------------------------------------------------------------------------
__global__ __launch_bounds__(256) void gemm_gates_k(
    const float* __restrict__ emb, const int* __restrict__ caption,
    const float* __restrict__ h_in,
    const float* __restrict__ W_ih, const float* __restrict__ W_hh,
    const float* __restrict__ b_ih, const float* __restrict__ b_hh,
    int t, float* __restrict__ gates) {
  __shared__ float As[16][65];
  __shared__ float Bs[16][65];
  int tid = threadIdx.x;
  int bx = blockIdx.x, by = blockIdx.y;
  int tx = tid & 15, ty = tid >> 4;
  float acc[4][4] = {};

  // caption index per loaded A-row is k-invariant: hoist
  int cap_m[4];
#pragma unroll
  for (int i = 0; i < 4; ++i) {
    int m = (tid + i * 256) >> 4;
    cap_m[i] = caption[(by * 64 + m) * TT_ + t];
  }

  for (int k0 = 0; k0 < EMB_ + MEM_; k0 += 16) {
#pragma unroll
    for (int i = 0; i < 4; ++i) {
      int idx = tid + i * 256;
      int m = idx >> 4, kk = idx & 15;
      int gm = by * 64 + m;
      int k = k0 + kk;
      float v;
      if (k < EMB_) v = emb[(size_t)cap_m[i] * EMB_ + k];
      else          v = h_in[(size_t)gm * MEM_ + (k - EMB_)];
      As[kk][m] = v;
    }
#pragma unroll
    for (int i = 0; i < 4; ++i) {
      int idx = tid + i * 256;
      int n = idx >> 4, kk = idx & 15;
      int gn = bx * 64 + n;
      int k = k0 + kk;
      float v;
      if (k < EMB_) v = W_ih[(size_t)gn * EMB_ + k];
      else          v = W_hh[(size_t)gn * MEM_ + (k - EMB_)];
      Bs[kk][n] = v;
    }
    __syncthreads();
#pragma unroll
    for (int kk = 0; kk < 16; ++kk) {
      float a[4], b[4];
#pragma unroll
      for (int i = 0; i < 4; ++i) a[i] = As[kk][ty * 4 + i];
#pragma unroll
      for (int j = 0; j < 4; ++j) b[j] = Bs[kk][tx * 4 + j];
#pragma unroll
      for (int i = 0; i < 4; ++i)
#pragma unroll
        for (int j = 0; j < 4; ++j) acc[i][j] += a[i] * b[j];
    }
    __syncthreads();
  }
#pragma unroll
  for (int i = 0; i < 4; ++i) {
    int gm = by * 64 + ty * 4 + i;
#pragma unroll
    for (int j = 0; j < 4; ++j) {
      int gn = bx * 64 + tx * 4 + j;
      gates[(size_t)gm * 4096 + gn] = acc[i][j] + b_ih[gn] + b_hh[gn];
    }
  }
}

// ---------------------------------------------------------------------------
// LSTM pointwise: i,f,g,o -> c_new, h_new.  256*1024 elements.
// ---------------------------------------------------------------------------
__global__ __launch_bounds__(256) void lstm_pointwise_k(
    const float* __restrict__ gates, const float* __restrict__ c_in,
    float* __restrict__ c_out, float* __restrict__ h_out) {
  int idx = blockIdx.x * 256 + threadIdx.x;  // 0..262143
  int b = idx >> 10, n = idx & 1023;
  const float* g = gates + (size_t)b * 4096;
  float ig = sigmoidf_(g[n]);
  float fg = sigmoidf_(g[MEM_ + n]);
  float gg = tanhf(g[2 * MEM_ + n]);
  float og = sigmoidf_(g[3 * MEM_ + n]);
  float c = fg * c_in[idx] + ig * gg;
  c_out[idx] = c;
  h_out[idx] = og * tanhf(c);
}

// ---------------------------------------------------------------------------
// Logits GEMM (M x 10000, K=1024) with fused per-row-tile LSE partials.
// Never materializes logits.  Rows: step_t>=0 -> row=b (fixed t);
// step_t<0 -> row = t*256+b.
// ---------------------------------------------------------------------------
__global__ __launch_bounds__(256) void logits_partial_k(
    const float* __restrict__ H, const float* __restrict__ Wout,
    const float* __restrict__ bout, const int* __restrict__ caption,
    int step_t, int M,
    float* __restrict__ pmax, float* __restrict__ psum, float* __restrict__ tlog) {
  __shared__ float As[16][65];
  __shared__ float Bs[16][65];
  __shared__ float Cs[64][65];
  int tid = threadIdx.x;
  int bx = blockIdx.x;  // vocab tile (0..156)
  int by = blockIdx.y;  // row tile
  int tx = tid & 15, ty = tid >> 4;
  float acc[4][4] = {};
  for (int k0 = 0; k0 < MEM_; k0 += 16) {
#pragma unroll
    for (int i = 0; i < 4; ++i) {
      int idx = tid + i * 256;
      int m = idx >> 4, kk = idx & 15;
      int gm = by * 64 + m;
      As[kk][m] = H[(size_t)gm * MEM_ + k0 + kk];
    }
#pragma unroll
    for (int i = 0; i < 4; ++i) {
      int idx = tid + i * 256;
      int n = idx >> 4, kk = idx & 15;
      int gn = bx * 64 + n;
      Bs[kk][n] = (gn < VOCAB_) ? Wout[(size_t)gn * MEM_ + k0 + kk] : 0.f;
    }
    __syncthreads();
#pragma unroll
    for (int kk = 0; kk < 16; ++kk) {
      float a[4], b[4];
#pragma unroll
      for (int i = 0; i < 4; ++i) a[i] = As[kk][ty * 4 + i];
#pragma unroll
      for (int j = 0; j < 4; ++j) b[j] = Bs[kk][tx * 4 + j];
#pragma unroll
      for (int i = 0; i < 4; ++i)
#pragma unroll
        for (int j = 0; j < 4; ++j) acc[i][j] += a[i] * b[j];
    }
    __syncthreads();
  }
#pragma unroll
  for (int i = 0; i < 4; ++i)
#pragma unroll
    for (int j = 0; j < 4; ++j) {
      int gn = bx * 64 + tx * 4 + j;
      Cs[ty * 4 + i][tx * 4 + j] = acc[i][j] + ((gn < VOCAB_) ? bout[gn] : 0.f);
    }
  __syncthreads();
  if (tid < 64) {
    int gm = by * 64 + tid;
    int nv = VOCAB_ - bx * 64; if (nv > 64) nv = 64;
    float m = -INFINITY;
    for (int j = 0; j < nv; ++j) m = fmaxf(m, Cs[tid][j]);
    float s = 0.f;
    for (int j = 0; j < nv; ++j) s += __expf(Cs[tid][j] - m);
    pmax[(size_t)gm * NTILE_V + bx] = m;
    psum[(size_t)gm * NTILE_V + bx] = s;
    int t = (step_t >= 0) ? step_t : (gm >> 8);
    int b = (step_t >= 0) ? gm : (gm & 255);
    int tgt = caption[b * TT_ + t + 1];
    int loc = tgt - bx * 64;
    if (loc >= 0 && loc < 64) tlog[gm] = Cs[tid][loc];
  }
}

// ---------------------------------------------------------------------------
// Combine partial LSE -> nll, masked accumulate
// ---------------------------------------------------------------------------
__global__ __launch_bounds__(256) void combine_k(
    const float* __restrict__ pmax, const float* __restrict__ psum,
    const float* __restrict__ tlog, const int* __restrict__ caption,
    int step_t, int M, float* __restrict__ accum) {
  int r = blockIdx.x * 256 + threadIdx.x;
  if (r >= M) return;
  const float* pm = pmax + (size_t)r * NTILE_V;
  const float* ps = psum + (size_t)r * NTILE_V;
  float m = -INFINITY;
  for (int j = 0; j < NTILE_V; ++j) m = fmaxf(m, pm[j]);
  float s = 0.f;
  for (int j = 0; j < NTILE_V; ++j) s += ps[j] * __expf(pm[j] - m);
  float lse = m + __logf(s);
  float nll = lse - tlog[r];
  int t = (step_t >= 0) ? step_t : (r >> 8);
  int b = (step_t >= 0) ? r : (r & 255);
  int tgt = caption[b * TT_ + t + 1];
  if (tgt != 0) {
    atomicAdd(&accum[0], nll);
    atomicAdd(&accum[1], 1.f);
  }
}

__global__ void zero_accum_k(float* accum) {
  if (threadIdx.x < 2) accum[threadIdx.x] = 0.f;
}

__global__ void finalize_k(const float* __restrict__ accum, float* __restrict__ out) {
  out[0] = accum[0] / fmaxf(accum[1], 1.0f);
}

// ---------------------------------------------------------------------------
extern "C" void kernel_launch(void* const* d_in, const int* in_sizes, int n_in,
                              void* d_out, int out_size, void* d_ws, size_t ws_size,
                              hipStream_t stream) {
  (void)in_sizes; (void)n_in; (void)out_size;
  const float* feature  = (const float*)d_in[0];
  const int*   caption  = (const int*)d_in[1];
  // d_in[2] = length (unused by reference)
  const float* W_init_h = (const float*)d_in[3];
  const float* b_init_h = (const float*)d_in[4];
  const float* W_init_c = (const float*)d_in[5];
  const float* b_init_c = (const float*)d_in[6];
  const float* emb      = (const float*)d_in[7];
  const float* W_ih     = (const float*)d_in[8];
  const float* b_ih     = (const float*)d_in[9];
  const float* W_hh     = (const float*)d_in[10];
  const float* b_hh     = (const float*)d_in[11];
  const float* W_out    = (const float*)d_in[12];
  const float* b_out    = (const float*)d_in[13];
  float* out = (float*)d_out;

  const size_t HC = (size_t)BS_ * MEM_;        // 262144
  const size_t GSZ = (size_t)BS_ * 4 * MEM_;   // 1048576
  float* ws = (float*)d_ws;
  float* h0    = ws;
  float* c_cur = h0 + HC;
  float* gates = c_cur + HC;
  float* base  = gates + GSZ;

  // big path sizes
  const size_t MBIG = (size_t)NSTEP * BS_;     // 7936
  size_t need_big = (base - ws) + MBIG * NTILE_V * 2 + MBIG + 2 + (size_t)NSTEP * HC;
  bool big = (ws_size >= need_big * sizeof(float));

  dim3 blk(256);

  zero_accum_k<<<1, blk, 0, stream>>>(big ? (base + MBIG * NTILE_V * 2 + MBIG)
                                          : (base + (size_t)BS_ * NTILE_V * 2 + BS_));

  // h0, c0
  {
    dim3 g(MEM_ / 64, BS_ / 64);
    gemm_nt_bias_k<<<g, blk, 0, stream>>>(feature, W_init_h, b_init_h, h0, BS_, MEM_, FEAT_);
    gemm_nt_bias_k<<<g, blk, 0, stream>>>(feature, W_init_c, b_init_c, c_cur, BS_, MEM_, FEAT_);
  }

  if (big) {
    float* pmax  = base;
    float* psum  = pmax + MBIG * NTILE_V;
    float* tlog  = psum + MBIG * NTILE_V;
    float* accum = tlog + MBIG;
    float* H_all = accum + 2;

    dim3 gg(4096 / 64, BS_ / 64);
    dim3 gl(HC / 256);
    for (int t = 0; t < NSTEP; ++t) {
      const float* h_in = (t == 0) ? h0 : (H_all + (size_t)(t - 1) * HC);
      float* h_out = H_all + (size_t)t * HC;
      gemm_gates_k<<<gg, blk, 0, stream>>>(emb, caption, h_in, W_ih, W_hh, b_ih, b_hh, t, gates);
      lstm_pointwise_k<<<gl, blk, 0, stream>>>(gates, c_cur, c_cur, h_out);
    }
    dim3 gp(NTILE_V, (unsigned)(MBIG / 64));
    logits_partial_k<<<gp, blk, 0, stream>>>(H_all, W_out, b_out, caption, -1, (int)MBIG,
                                             pmax, psum, tlog);
    dim3 gc((unsigned)((MBIG + 255) / 256));
    combine_k<<<gc, blk, 0, stream>>>(pmax, psum, tlog, caption, -1, (int)MBIG, accum);
    finalize_k<<<1, 1, 0, stream>>>(accum, out);
  } else {
    float* pmax  = base;
    float* psum  = pmax + (size_t)BS_ * NTILE_V;
    float* tlog  = psum + (size_t)BS_ * NTILE_V;
    float* accum = tlog + BS_;
    float* h_cur = accum + 2;

    dim3 gg(4096 / 64, BS_ / 64);
    dim3 gl(HC / 256);
    dim3 gp(NTILE_V, BS_ / 64);
    for (int t = 0; t < NSTEP; ++t) {
      const float* h_in = (t == 0) ? h0 : h_cur;
      gemm_gates_k<<<gg, blk, 0, stream>>>(emb, caption, h_in, W_ih, W_hh, b_ih, b_hh, t, gates);
      lstm_pointwise_k<<<gl, blk, 0, stream>>>(gates, c_cur, c_cur, h_cur);
      logits_partial_k<<<gp, blk, 0, stream>>>(h_cur, W_out, b_out, caption, t, BS_,
                                               pmax, psum, tlog);
      combine_k<<<1, blk, 0, stream>>>(pmax, psum, tlog, caption, t, BS_, accum);
    }
    finalize_k<<<1, 1, 0, stream>>>(accum, out);
  }
}

// Round 2
// 1749.693 us; speedup vs baseline: 4.5076x; 4.5076x over previous
//
#include <hip/hip_runtime.h>
#include <math.h>

#define BS_    256
#define FEAT_  2048
#define EMB_   512
#define MEM_   1024
#define VOCAB_ 10000
#define TT_    32
#define NSTEP  31
#define VT_    128
#define NTV_   79      // ceil(10000/128)
#define MROWS_ 7936    // 31*256

typedef unsigned short u16;
typedef __bf16 bf16x8 __attribute__((ext_vector_type(8)));
typedef float  f32x4  __attribute__((ext_vector_type(4)));
typedef u16    u16x8  __attribute__((ext_vector_type(8)));
typedef u16    u16x4  __attribute__((ext_vector_type(4)));
typedef bf16x8 __attribute__((may_alias)) bf16x8_ma;
typedef u16x8  __attribute__((may_alias)) u16x8_ma;
typedef u16x4  __attribute__((may_alias)) u16x4_ma;
typedef float4 __attribute__((may_alias)) float4_ma;

__device__ __forceinline__ u16 f2bf(float f) {
  unsigned u = __float_as_uint(f);
  u += 0x7FFFu + ((u >> 16) & 1u);
  return (u16)(u >> 16);
}

__device__ __forceinline__ void async16(const void* g, void* s) {
  __builtin_amdgcn_global_load_lds((const __attribute__((address_space(1))) void*)g,
                                   (__attribute__((address_space(3))) void*)s, 16, 0, 0);
}

__device__ __forceinline__ float redmax16(float v) {
#pragma unroll
  for (int m = 1; m < 16; m <<= 1) v = fmaxf(v, __shfl_xor(v, m, 64));
  return v;
}
__device__ __forceinline__ float redsum16(float v) {
#pragma unroll
  for (int m = 1; m < 16; m <<= 1) v += __shfl_xor(v, m, 64);
  return v;
}
__device__ __forceinline__ float sigmoidf_(float x) { return 1.0f / (1.0f + __expf(-x)); }

// ---------------------------------------------------------------------------
// fp32 -> bf16 bulk convert (x4 vectorized)
// ---------------------------------------------------------------------------
__global__ __launch_bounds__(256) void cvt_bf16_k(const float* __restrict__ in,
                                                  u16* __restrict__ out, int n4) {
  int i = blockIdx.x * 256 + threadIdx.x;
  if (i >= n4) return;
  float4 v = ((const float4_ma*)in)[i];
  u16x4 o = { f2bf(v.x), f2bf(v.y), f2bf(v.z), f2bf(v.w) };
  *(u16x4_ma*)(out + (size_t)i * 4) = o;
}

// ---------------------------------------------------------------------------
// Gather all step embeddings: X_all[t][b][e] = bf16(emb[caption[b][t]][e])
// i indexes (t, b, e/4); total = 31*256*128 = 1,015,808 threads
// ---------------------------------------------------------------------------
__global__ __launch_bounds__(256) void gather_x_k(const float* __restrict__ emb,
                                                  const int* __restrict__ caption,
                                                  u16* __restrict__ X) {
  int i = blockIdx.x * 256 + threadIdx.x;
  int e4 = (i & 127) * 4;
  int b  = (i >> 7) & 255;
  int t  = i >> 15;
  int cap = caption[b * TT_ + t];
  float4 v = *(const float4_ma*)(emb + (size_t)cap * EMB_ + e4);
  u16x4 o = { f2bf(v.x), f2bf(v.y), f2bf(v.z), f2bf(v.w) };
  *(u16x4_ma*)(X + ((size_t)(t * 256 + b) * EMB_ + e4)) = o;
}

// ---------------------------------------------------------------------------
// fp32 vector GEMM for init: C = A(MxK) @ B(NxK)^T + bias.
// C (fp32) optional, Cb (bf16) optional.
// ---------------------------------------------------------------------------
__global__ __launch_bounds__(256) void gemm_nt_bias_k(
    const float* __restrict__ A, const float* __restrict__ B,
    const float* __restrict__ bias, float* __restrict__ C, u16* __restrict__ Cb,
    int M, int N, int K) {
  __shared__ float As[16][65];
  __shared__ float Bs[16][65];
  int tid = threadIdx.x;
  int bx = blockIdx.x, by = blockIdx.y;
  int tx = tid & 15, ty = tid >> 4;
  float acc[4][4] = {};
  for (int k0 = 0; k0 < K; k0 += 16) {
#pragma unroll
    for (int i = 0; i < 4; ++i) {
      int idx = tid + i * 256;
      int m = idx >> 4, kk = idx & 15;
      As[kk][m] = A[(size_t)(by * 64 + m) * K + k0 + kk];
    }
#pragma unroll
    for (int i = 0; i < 4; ++i) {
      int idx = tid + i * 256;
      int n = idx >> 4, kk = idx & 15;
      Bs[kk][n] = B[(size_t)(bx * 64 + n) * K + k0 + kk];
    }
    __syncthreads();
#pragma unroll
    for (int kk = 0; kk < 16; ++kk) {
      float a[4], b[4];
#pragma unroll
      for (int i = 0; i < 4; ++i) a[i] = As[kk][ty * 4 + i];
#pragma unroll
      for (int j = 0; j < 4; ++j) b[j] = Bs[kk][tx * 4 + j];
#pragma unroll
      for (int i = 0; i < 4; ++i)
#pragma unroll
        for (int j = 0; j < 4; ++j) acc[i][j] += a[i] * b[j];
    }
    __syncthreads();
  }
#pragma unroll
  for (int i = 0; i < 4; ++i) {
    int gm = by * 64 + ty * 4 + i;
#pragma unroll
    for (int j = 0; j < 4; ++j) {
      int gn = bx * 64 + tx * 4 + j;
      float v = acc[i][j] + bias[gn];
      if (C)  C[(size_t)gm * N + gn] = v;
      if (Cb) Cb[(size_t)gm * N + gn] = f2bf(v);
    }
  }
}

// ---------------------------------------------------------------------------
// MFMA gates GEMM: gates[256][4096] = [X_t | H_t] @ [W_ih | W_hh]^T + b_ih + b_hh
// Tile 64x128, 128 threads (2 waves), BK=32, K=1536.  Grid (32, 4).
// ---------------------------------------------------------------------------
__global__ __launch_bounds__(128) void mfma_gates_k(
    const u16* __restrict__ Xt,   // [256][512]
    const u16* __restrict__ Ht,   // [256][1024]
    const u16* __restrict__ WihB, // [4096][512]
    const u16* __restrict__ WhhB, // [4096][1024]
    const float* __restrict__ b_ih, const float* __restrict__ b_hh,
    float* __restrict__ gates) {
  __shared__ __align__(16) char smem[12288];
  u16* sA = (u16*)smem;            // [64][32]
  u16* sB = (u16*)(smem + 4096);   // [128][32]
  const int tid = threadIdx.x;
  const int n0 = blockIdx.x * 128;
  const int m0 = blockIdx.y * 64;
  const int l = tid & 63, wid = tid >> 6;
  const int wn = wid * 64;
  const int q = l >> 4, ln = l & 15;

  f32x4 acc[4][4];
  const f32x4 z = {0.f, 0.f, 0.f, 0.f};
#pragma unroll
  for (int i = 0; i < 4; ++i)
#pragma unroll
    for (int j = 0; j < 4; ++j) acc[i][j] = z;

  const int srow = tid >> 2;        // 0..31
  const int scol = (tid & 3) * 8;   // k elem offset

  for (int k0 = 0; k0 < EMB_ + MEM_; k0 += 32) {
    const bool first = (k0 < EMB_);
    const u16* Asrc = first ? Xt : Ht;
    const u16* Bsrc = first ? WihB : WhhB;
    const int str = first ? EMB_ : MEM_;
    const int ak = first ? k0 : (k0 - EMB_);
#pragma unroll
    for (int r = 0; r < 2; ++r)
      async16(Asrc + (size_t)(m0 + srow + r * 32) * str + ak + scol,
              sA + (srow + r * 32) * 32 + scol);
#pragma unroll
    for (int r = 0; r < 4; ++r)
      async16(Bsrc + (size_t)(n0 + srow + r * 32) * str + ak + scol,
              sB + (srow + r * 32) * 32 + scol);
    __syncthreads();
    bf16x8 a[4], b[4];
#pragma unroll
    for (int i = 0; i < 4; ++i) a[i] = *(const bf16x8_ma*)(sA + (i * 16 + ln) * 32 + q * 8);
#pragma unroll
    for (int j = 0; j < 4; ++j) b[j] = *(const bf16x8_ma*)(sB + (wn + j * 16 + ln) * 32 + q * 8);
#pragma unroll
    for (int i = 0; i < 4; ++i)
#pragma unroll
      for (int j = 0; j < 4; ++j)
        acc[i][j] = __builtin_amdgcn_mfma_f32_16x16x32_bf16(a[i], b[j], acc[i][j], 0, 0, 0);
    __syncthreads();
  }

  int colj[4]; float bj[4];
#pragma unroll
  for (int j = 0; j < 4; ++j) {
    colj[j] = n0 + wn + j * 16 + ln;
    bj[j] = b_ih[colj[j]] + b_hh[colj[j]];
  }
#pragma unroll
  for (int i = 0; i < 4; ++i)
#pragma unroll
    for (int r = 0; r < 4; ++r) {
      int grow = m0 + i * 16 + q * 4 + r;
#pragma unroll
      for (int j = 0; j < 4; ++j)
        gates[(size_t)grow * 4096 + colj[j]] = acc[i][j][r] + bj[j];
    }
}

// ---------------------------------------------------------------------------
// LSTM pointwise; h written as bf16
// ---------------------------------------------------------------------------
__global__ __launch_bounds__(256) void lstm_pointwise_k(
    const float* __restrict__ gates, const float* __restrict__ c_in,
    float* __restrict__ c_out, u16* __restrict__ h_out) {
  int idx = blockIdx.x * 256 + threadIdx.x;
  int b = idx >> 10, n = idx & 1023;
  const float* g = gates + (size_t)b * 4096;
  float ig = sigmoidf_(g[n]);
  float fg = sigmoidf_(g[MEM_ + n]);
  float gg = tanhf(g[2 * MEM_ + n]);
  float og = sigmoidf_(g[3 * MEM_ + n]);
  float c = fg * c_in[idx] + ig * gg;
  c_out[idx] = c;
  h_out[idx] = f2bf(og * tanhf(c));
}

// ---------------------------------------------------------------------------
// MFMA logits GEMM + fused LSE partials.  Tile 128x128, 256 thr (4 waves),
// BK=32, K=1024.  Grid (NTV_, 62).  CONVB=1: stage-convert W_out fp32 inline.
// ---------------------------------------------------------------------------
template <int CONVB>
__global__ __launch_bounds__(256) void mfma_logits_k(
    const u16* __restrict__ H,       // [7936][1024] bf16 (slots 1..31)
    const u16* __restrict__ WoutB,   // [10000][1024] bf16 (CONVB=0)
    const float* __restrict__ WoutF, // fp32 (CONVB=1)
    const float* __restrict__ bout,
    const int* __restrict__ caption,
    float* __restrict__ pmax, float* __restrict__ psum, float* __restrict__ tlog) {
  __shared__ __align__(16) char smem[16384];
  u16* sA = (u16*)smem;            // [128][32]
  u16* sB = (u16*)(smem + 8192);   // [128][32]
  const int tid = threadIdx.x;
  const int n0 = blockIdx.x * VT_;
  const int m0 = blockIdx.y * 128;
  const int l = tid & 63, wid = tid >> 6;
  const int wm = (wid & 1) * 64, wn = (wid >> 1) * 64;
  const int q = l >> 4, ln = l & 15;

  f32x4 acc[4][4];
  const f32x4 z = {0.f, 0.f, 0.f, 0.f};
#pragma unroll
  for (int i = 0; i < 4; ++i)
#pragma unroll
    for (int j = 0; j < 4; ++j) acc[i][j] = z;

  const int srow = tid >> 2;        // 0..63
  const int scol = (tid & 3) * 8;

  int brow[2];
#pragma unroll
  for (int r = 0; r < 2; ++r) {
    int gr = n0 + srow + r * 64;
    brow[r] = (gr > VOCAB_ - 1) ? (VOCAB_ - 1) : gr;
  }

  for (int k0 = 0; k0 < MEM_; k0 += 32) {
#pragma unroll
    for (int r = 0; r < 2; ++r)
      async16(H + (size_t)(m0 + srow + r * 64) * MEM_ + k0 + scol,
              sA + (srow + r * 64) * 32 + scol);
    if (CONVB) {
#pragma unroll
      for (int r = 0; r < 2; ++r) {
        const float* g = WoutF + (size_t)brow[r] * MEM_ + k0 + scol;
        float4 v0 = *(const float4_ma*)g;
        float4 v1 = *(const float4_ma*)(g + 4);
        u16x8 o = { f2bf(v0.x), f2bf(v0.y), f2bf(v0.z), f2bf(v0.w),
                    f2bf(v1.x), f2bf(v1.y), f2bf(v1.z), f2bf(v1.w) };
        *(u16x8_ma*)(sB + (srow + r * 64) * 32 + scol) = o;
      }
    } else {
#pragma unroll
      for (int r = 0; r < 2; ++r)
        async16(WoutB + (size_t)brow[r] * MEM_ + k0 + scol,
                sB + (srow + r * 64) * 32 + scol);
    }
    __syncthreads();
    bf16x8 a[4], b[4];
#pragma unroll
    for (int i = 0; i < 4; ++i) a[i] = *(const bf16x8_ma*)(sA + (wm + i * 16 + ln) * 32 + q * 8);
#pragma unroll
    for (int j = 0; j < 4; ++j) b[j] = *(const bf16x8_ma*)(sB + (wn + j * 16 + ln) * 32 + q * 8);
#pragma unroll
    for (int i = 0; i < 4; ++i)
#pragma unroll
      for (int j = 0; j < 4; ++j)
        acc[i][j] = __builtin_amdgcn_mfma_f32_16x16x32_bf16(a[i], b[j], acc[i][j], 0, 0, 0);
    __syncthreads();
  }

  // ---- fused LSE epilogue (reuse smem) ----
  float* eM = (float*)smem;        // [128][2]
  float* eS = eM + 256;
  float* eT = eS + 256;
  const int half = wid >> 1;

  int colj[4]; float bj[4];
#pragma unroll
  for (int j = 0; j < 4; ++j) {
    colj[j] = n0 + wn + j * 16 + ln;
    bj[j] = (colj[j] < VOCAB_) ? bout[colj[j]] : 0.f;
  }
#pragma unroll
  for (int i = 0; i < 4; ++i) {
#pragma unroll
    for (int r = 0; r < 4; ++r) {
      const int rloc = wm + i * 16 + q * 4 + r;
      const int trow = m0 + rloc;
      const int tgt = caption[(trow & 255) * TT_ + (trow >> 8) + 1];
      float v[4];
#pragma unroll
      for (int j = 0; j < 4; ++j)
        v[j] = (colj[j] < VOCAB_) ? (acc[i][j][r] + bj[j]) : -INFINITY;
      float mx = fmaxf(fmaxf(v[0], v[1]), fmaxf(v[2], v[3]));
      mx = redmax16(mx);
      mx = fmaxf(mx, -1e30f);   // all-invalid guard (last vocab tile)
      float s = 0.f, tv = 0.f;
#pragma unroll
      for (int j = 0; j < 4; ++j) {
        s += __expf(v[j] - mx);
        if (colj[j] == tgt) tv += v[j];
      }
      s = redsum16(s);
      tv = redsum16(tv);
      if (ln == 0) {
        eM[rloc * 2 + half] = mx;
        eS[rloc * 2 + half] = s;
        eT[rloc * 2 + half] = tv;
      }
    }
  }
  __syncthreads();
  if (tid < 128) {
    int trow = m0 + tid;
    float m0v = eM[tid * 2], m1v = eM[tid * 2 + 1];
    float M = fmaxf(m0v, m1v);
    float S = eS[tid * 2] * __expf(m0v - M) + eS[tid * 2 + 1] * __expf(m1v - M);
    pmax[(size_t)trow * NTV_ + blockIdx.x] = M;
    psum[(size_t)trow * NTV_ + blockIdx.x] = S;
    int tgt = caption[(trow & 255) * TT_ + (trow >> 8) + 1];
    if (tgt >= n0 && tgt < n0 + VT_) tlog[trow] = eT[tid * 2] + eT[tid * 2 + 1];
  }
}

// ---------------------------------------------------------------------------
__global__ __launch_bounds__(256) void combine_k(
    const float* __restrict__ pmax, const float* __restrict__ psum,
    const float* __restrict__ tlog, const int* __restrict__ caption,
    float* __restrict__ accum) {
  int r = blockIdx.x * 256 + threadIdx.x;
  if (r >= MROWS_) return;
  const float* pm = pmax + (size_t)r * NTV_;
  const float* ps = psum + (size_t)r * NTV_;
  float m = -INFINITY;
  for (int j = 0; j < NTV_; ++j) m = fmaxf(m, pm[j]);
  float s = 0.f;
  for (int j = 0; j < NTV_; ++j) s += ps[j] * __expf(pm[j] - m);
  float nll = m + __logf(s) - tlog[r];
  int tgt = caption[(r & 255) * TT_ + (r >> 8) + 1];
  if (tgt != 0) {
    atomicAdd(&accum[0], nll);
    atomicAdd(&accum[1], 1.f);
  }
}

__global__ void zero_accum_k(float* accum) {
  if (threadIdx.x < 2) accum[threadIdx.x] = 0.f;
}

__global__ void finalize_k(const float* __restrict__ accum, float* __restrict__ out) {
  out[0] = accum[0] / fmaxf(accum[1], 1.0f);
}

// ---------------------------------------------------------------------------
extern "C" void kernel_launch(void* const* d_in, const int* in_sizes, int n_in,
                              void* d_out, int out_size, void* d_ws, size_t ws_size,
                              hipStream_t stream) {
  (void)in_sizes; (void)n_in; (void)out_size;
  const float* feature  = (const float*)d_in[0];
  const int*   caption  = (const int*)d_in[1];
  const float* W_init_h = (const float*)d_in[3];
  const float* b_init_h = (const float*)d_in[4];
  const float* W_init_c = (const float*)d_in[5];
  const float* b_init_c = (const float*)d_in[6];
  const float* emb      = (const float*)d_in[7];
  const float* W_ih     = (const float*)d_in[8];
  const float* b_ih     = (const float*)d_in[9];
  const float* W_hh     = (const float*)d_in[10];
  const float* b_hh     = (const float*)d_in[11];
  const float* W_out    = (const float*)d_in[12];
  const float* b_out    = (const float*)d_in[13];
  float* out = (float*)d_out;

  char* p = (char*)d_ws;
  u16* WihB = (u16*)p;       p += (size_t)4096 * 512 * 2;
  u16* WhhB = (u16*)p;       p += (size_t)4096 * 1024 * 2;
  u16* Xall = (u16*)p;       p += (size_t)NSTEP * 256 * 512 * 2;
  u16* Hall = (u16*)p;       p += (size_t)32 * 256 * 1024 * 2;
  float* c_cur = (float*)p;  p += (size_t)256 * 1024 * 4;
  float* gates = (float*)p;  p += (size_t)256 * 4096 * 4;
  float* pmax = (float*)p;   p += (size_t)MROWS_ * NTV_ * 4;
  float* psum = (float*)p;   p += (size_t)MROWS_ * NTV_ * 4;
  float* tlog = (float*)p;   p += (size_t)MROWS_ * 4;
  float* accum = (float*)p;  p += 16;
  size_t used = (size_t)(p - (char*)d_ws);
  u16* WoutB = (u16*)p;
  bool haveWoutB = (ws_size >= used + (size_t)VOCAB_ * 1024 * 2);

  dim3 blk(256);
  zero_accum_k<<<1, 64, 0, stream>>>(accum);
  cvt_bf16_k<<<2048, blk, 0, stream>>>(W_ih, WihB, 524288);
  cvt_bf16_k<<<4096, blk, 0, stream>>>(W_hh, WhhB, 1048576);
  if (haveWoutB) cvt_bf16_k<<<10000, blk, 0, stream>>>(W_out, WoutB, 2560000);
  gather_x_k<<<3968, blk, 0, stream>>>(emb, caption, Xall);

  {
    dim3 gi(MEM_ / 64, BS_ / 64);
    gemm_nt_bias_k<<<gi, blk, 0, stream>>>(feature, W_init_h, b_init_h, nullptr, Hall,
                                           BS_, MEM_, FEAT_);
    gemm_nt_bias_k<<<gi, blk, 0, stream>>>(feature, W_init_c, b_init_c, c_cur, nullptr,
                                           BS_, MEM_, FEAT_);
  }

  dim3 gg(32, 4), gl(1024);
  for (int t = 0; t < NSTEP; ++t) {
    mfma_gates_k<<<gg, dim3(128), 0, stream>>>(Xall + (size_t)t * 256 * 512,
                                               Hall + (size_t)t * 256 * 1024,
                                               WihB, WhhB, b_ih, b_hh, gates);
    lstm_pointwise_k<<<gl, blk, 0, stream>>>(gates, c_cur, c_cur,
                                             Hall + (size_t)(t + 1) * 256 * 1024);
  }

  dim3 gp(NTV_, MROWS_ / 128);
  if (haveWoutB)
    mfma_logits_k<0><<<gp, blk, 0, stream>>>(Hall + (size_t)256 * 1024, WoutB, W_out,
                                             b_out, caption, pmax, psum, tlog);
  else
    mfma_logits_k<1><<<gp, blk, 0, stream>>>(Hall + (size_t)256 * 1024, WoutB, W_out,
                                             b_out, caption, pmax, psum, tlog);

  combine_k<<<31, blk, 0, stream>>>(pmax, psum, tlog, caption, accum);
  finalize_k<<<1, 1, 0, stream>>>(accum, out);
}